// Round 5
// baseline (1670.855 us; speedup 1.0000x reference)
//
#include <hip/hip_runtime.h>

typedef unsigned short u16;
typedef unsigned int   u32;
typedef short  bf16x8 __attribute__((ext_vector_type(8)));
typedef float  f32x4  __attribute__((ext_vector_type(4)));

#define T_SEQ 256
#define BATCH 1024
#define HID   128

__device__ __forceinline__ u16 f2bf(float f) {
  u32 x = __builtin_bit_cast(u32, f);
  x = x + 0x7fffu + ((x >> 16) & 1u);   // round-to-nearest-even
  return (u16)(x >> 16);
}
__device__ __forceinline__ float bf2f(u16 v) {
  u32 x = ((u32)v) << 16;
  return __builtin_bit_cast(float, x);
}
__device__ __forceinline__ float sigm(float x) {
  return 1.0f / (1.0f + __expf(-x));
}
__device__ __forceinline__ float tanh_f(float x) {
  return 2.0f / (1.0f + __expf(-2.0f * x)) - 1.0f;
}

// ---------------------------------------------------------------------------
// Convert x_in (fp32, T*B*S = 16,777,216 elems) -> bf16, 4 elems/thread.
// ---------------------------------------------------------------------------
__global__ void conv_x_kernel(const float* __restrict__ x_in, u16* __restrict__ xb) {
  int i = (blockIdx.x * blockDim.x + threadIdx.x) * 4;
  float4 v = *(const float4*)(x_in + i);
  u32 lo = (u32)f2bf(v.x) | ((u32)f2bf(v.y) << 16);
  u32 hi = (u32)f2bf(v.z) | ((u32)f2bf(v.w) << 16);
  *(u32*)(xb + i) = lo;
  *(u32*)(xb + i + 2) = hi;
}

// ---------------------------------------------------------------------------
// Prep: gather weights into NATURAL-order MFMA B-fragments (no gate permute).
// Wave n (0..15) owns gate cols [n*32, n*32+32); tile t2 covers
// [n*32+t2*16, +16). Fragment element (lane,e): col=lane&15, quad=lane>>4;
//   gate row r = n*32 + tile*16 + col ; k = kk*32 + quad*8 + e
// flat frag index: (((n*2+tile)*KK + kk)*64 + lane)*8 + e
// WcP = w_ih0 @ pre_w (K=64, KK=2); bias0 = w_ih0@pre_b + b_ih0 + b_hh0
// (natural gate order: bias0[r], r in [0,512)).
// ---------------------------------------------------------------------------
__global__ void prep_kernel(const float* __restrict__ pre_w, const float* __restrict__ pre_b,
                            const float* __restrict__ w_ih0, const float* __restrict__ w_hh0,
                            const float* __restrict__ b_ih0, const float* __restrict__ b_hh0,
                            const float* __restrict__ w_ih1, const float* __restrict__ w_hh1,
                            const float* __restrict__ b_ih1, const float* __restrict__ b_hh1,
                            u16* __restrict__ WcP, u16* __restrict__ WhhP0,
                            u16* __restrict__ WihP1, u16* __restrict__ WhhP1,
                            float* __restrict__ bias0, float* __restrict__ bias1) {
  const int TOT = 230400;
  for (int idx = blockIdx.x * blockDim.x + threadIdx.x; idx < TOT;
       idx += gridDim.x * blockDim.x) {
    if (idx < 32768) {                       // WcP (KK=2)
      int e = idx & 7, lane = (idx >> 3) & 63, kk = (idx >> 9) & 1,
          tile = (idx >> 10) & 1, n = idx >> 11;
      int r = n * 32 + tile * 16 + (lane & 15);
      int k = kk * 32 + (lane >> 4) * 8 + e;
      float s = 0.f;
      for (int h = 0; h < 128; ++h)
        s += w_ih0[r * 128 + h] * pre_w[h * 64 + k];
      WcP[idx] = f2bf(s);
    } else if (idx < 33280) {                // bias0 natural order (fp32)
      int r = idx - 32768;
      float s = b_ih0[r] + b_hh0[r];
      for (int h = 0; h < 128; ++h)
        s += w_ih0[r * 128 + h] * pre_b[h];
      bias0[r] = s;
    } else if (idx < 229888) {               // 3 natural-frag bf16 copies (KK=4)
      int q = idx - 33280;
      int mat = q / 65536; q = q % 65536;
      int e = q & 7, lane = (q >> 3) & 63, kk = (q >> 9) & 3,
          tile = (q >> 11) & 1, n = q >> 12;
      int r = n * 32 + tile * 16 + (lane & 15);
      int k = kk * 32 + (lane >> 4) * 8 + e;
      const float* src = mat == 0 ? w_hh0 : (mat == 1 ? w_ih1 : w_hh1);
      u16* dst = mat == 0 ? WhhP0 : (mat == 1 ? WihP1 : WhhP1);
      dst[q] = f2bf(src[r * 128 + k]);
    } else {                                 // bias1 natural order (fp32)
      int r = idx - 229888;
      bias1[r] = b_ih1[r] + b_hh1[r];
    }
  }
}

// ---------------------------------------------------------------------------
// Fused LSTM layer scan — correctness-first structure, FP32 outputs.
// 64 WGs x 1024 thr; WG = 16 batch rows. MFMA role: wave n computes gate
// preacts for cols [n*32,n*32+32) (acc0: first 16, acc1: second 16), with
// A = [16 batch rows] x K from xb/hbuf, B = natural weight frags in VGPRs.
// All 16x512 f32 preacts go to gbuf (padded). Barrier. Pointwise role:
// thread (wave=batch row m, lane -> h cols j0=2*lane, j1=j0+1) reads its own
// i/f/g/o from gbuf, updates fp32 c-state in registers, writes h (bf16) to
// hbuf (padded, stride 136). Barrier. Repeat.
// d_out is FP32 (reference output dtype): pred[1024] | h_t[2,1024,128] |
// c_t[2,1024,128], flat concat.
// ---------------------------------------------------------------------------
template <int KKI, bool WRITE_Y, bool IS_L1>
__global__ __launch_bounds__(1024) void lstm_scan(
    const u16* __restrict__ xsrc,   // [T*B, KIN] row-major bf16
    const u16* __restrict__ WihF, const u16* __restrict__ WhhF,
    const float* __restrict__ biasP,
    const float* __restrict__ h0_in, const float* __restrict__ c0_in,
    u16* __restrict__ y_out, float* __restrict__ dout,
    const float* __restrict__ post_w, const float* __restrict__ post_b) {
  constexpr int KIN = KKI * 32;
  constexpr int LAYER = IS_L1 ? 1 : 0;
  const int b0 = blockIdx.x * 16;
  const int tid = threadIdx.x, wave = tid >> 6, lane = tid & 63;
  const int col = lane & 15, quad = lane >> 4;

  __shared__ float gbuf[16][516];               // [batch row][512 gate preacts + pad]
  __shared__ __align__(16) u16 hbuf[16 * 136];  // row m at m*136, 128 h + 8 pad

  // ---- MFMA-role setup: natural-order weight fragments in VGPRs ----
  bf16x8 wih[2][KKI], whh[2][4];
#pragma unroll
  for (int t2 = 0; t2 < 2; ++t2)
#pragma unroll
    for (int kk = 0; kk < KKI; ++kk)
      wih[t2][kk] = *(const bf16x8*)(WihF + (((wave * 2 + t2) * KKI + kk) * 64 + lane) * 8);
#pragma unroll
  for (int t2 = 0; t2 < 2; ++t2)
#pragma unroll
    for (int kk = 0; kk < 4; ++kk)
      whh[t2][kk] = *(const bf16x8*)(WhhF + (((wave * 2 + t2) * 4 + kk) * 64 + lane) * 8);
  const float bias_t0 = biasP[wave * 32 + col];        // gate col wave*32+col
  const float bias_t1 = biasP[wave * 32 + 16 + col];   // gate col wave*32+16+col

  // ---- pointwise-role setup: batch row m=wave, h cols j0=2*lane, j1=j0+1 ----
  const int j0 = 2 * lane;
  float cst0 = c0_in[(LAYER * BATCH + b0 + wave) * HID + j0];
  float cst1 = c0_in[(LAYER * BATCH + b0 + wave) * HID + j0 + 1];
  float h0f = h0_in[(LAYER * BATCH + b0 + wave) * HID + j0];
  float h1f = h0_in[(LAYER * BATCH + b0 + wave) * HID + j0 + 1];

  {  // init hbuf = h0 (bf16)
    u32 v = (u32)f2bf(h0f) | ((u32)f2bf(h1f) << 16);
    *(u32*)&hbuf[wave * 136 + j0] = v;
  }
  __syncthreads();

  const u16* xrow = xsrc + (b0 + col) * KIN;   // A-frag row m=col -> batch b0+col

  for (int t = 0; t < T_SEQ; ++t) {
    // A-fragments: A[m=col][k=quad*8+e] per K=32 slice kk
    bf16x8 ax[KKI], ah[4];
#pragma unroll
    for (int kk = 0; kk < KKI; ++kk)
      ax[kk] = *(const bf16x8*)(xrow + kk * 32 + quad * 8);
#pragma unroll
    for (int kk = 0; kk < 4; ++kk)
      ah[kk] = *(const bf16x8*)&hbuf[col * 136 + (kk * 4 + quad) * 8];

    f32x4 acc0 = {bias_t0, bias_t0, bias_t0, bias_t0};
    f32x4 acc1 = {bias_t1, bias_t1, bias_t1, bias_t1};
#pragma unroll
    for (int kk = 0; kk < KKI; ++kk) {
      acc0 = __builtin_amdgcn_mfma_f32_16x16x32_bf16(ax[kk], wih[0][kk], acc0, 0, 0, 0);
      acc1 = __builtin_amdgcn_mfma_f32_16x16x32_bf16(ax[kk], wih[1][kk], acc1, 0, 0, 0);
    }
#pragma unroll
    for (int kk = 0; kk < 4; ++kk) {
      acc0 = __builtin_amdgcn_mfma_f32_16x16x32_bf16(ah[kk], whh[0][kk], acc0, 0, 0, 0);
      acc1 = __builtin_amdgcn_mfma_f32_16x16x32_bf16(ah[kk], whh[1][kk], acc1, 0, 0, 0);
    }
    // D layout: row (batch) = quad*4+reg, col (gate) = lane&15 [m89/m91]
#pragma unroll
    for (int r = 0; r < 4; ++r) {
      gbuf[quad * 4 + r][wave * 32 + col]      = acc0[r];
      gbuf[quad * 4 + r][wave * 32 + 16 + col] = acc1[r];
    }
    __syncthreads();

    // pointwise: i,f,g,o for (m=wave, j0), (m=wave, j1)
    float2 gi = *(const float2*)&gbuf[wave][0   + j0];
    float2 gf = *(const float2*)&gbuf[wave][128 + j0];
    float2 gg = *(const float2*)&gbuf[wave][256 + j0];
    float2 go = *(const float2*)&gbuf[wave][384 + j0];
    float i0 = sigm(gi.x), f0 = sigm(gf.x), g0 = tanh_f(gg.x), o0 = sigm(go.x);
    float i1 = sigm(gi.y), f1 = sigm(gf.y), g1 = tanh_f(gg.y), o1 = sigm(go.y);
    cst0 = f0 * cst0 + i0 * g0;
    cst1 = f1 * cst1 + i1 * g1;
    h0f = o0 * tanh_f(cst0);
    h1f = o1 * tanh_f(cst1);
    u32 hv = (u32)f2bf(h0f) | ((u32)f2bf(h1f) << 16);
    *(u32*)&hbuf[wave * 136 + j0] = hv;
    if (WRITE_Y)
      *(u32*)(y_out + (t * BATCH + b0 + wave) * HID + j0) = hv;
    __syncthreads();

    xrow += BATCH * KIN;
  }

  // ---- finals straight from fp32 pointwise registers (FP32 output!) ----
  // h_t at fp32 offset 1024 + layer*B*H ; c_t at 1024 + 2*B*H + layer*B*H
  float2 hpair = {h0f, h1f};
  float2 cpair = {cst0, cst1};
  *(float2*)(dout + BATCH + LAYER * (BATCH * HID) + (b0 + wave) * HID + j0) = hpair;
  *(float2*)(dout + BATCH + 2 * BATCH * HID + LAYER * (BATCH * HID) + (b0 + wave) * HID + j0) = cpair;

  if (IS_L1) {  // pred[b] = relu(h1_T[b]) . post_w + post_b ; wave -> batch b0+wave
    float a0 = fmaxf(h0f, 0.f);
    float a1 = fmaxf(h1f, 0.f);
    float p = a0 * post_w[j0] + a1 * post_w[j0 + 1];
#pragma unroll
    for (int off = 32; off > 0; off >>= 1) p += __shfl_down(p, off, 64);
    if (lane == 0) dout[b0 + wave] = p + post_b[0];
  }
}

extern "C" void kernel_launch(void* const* d_in, const int* in_sizes, int n_in,
                              void* d_out, int out_size, void* d_ws, size_t ws_size,
                              hipStream_t stream) {
  const float* x_in  = (const float*)d_in[0];
  const float* h0    = (const float*)d_in[1];
  const float* c0    = (const float*)d_in[2];
  const float* pre_w = (const float*)d_in[3];
  const float* pre_b = (const float*)d_in[4];
  const float* w_ih0 = (const float*)d_in[5];
  const float* w_hh0 = (const float*)d_in[6];
  const float* b_ih0 = (const float*)d_in[7];
  const float* b_hh0 = (const float*)d_in[8];
  const float* w_ih1 = (const float*)d_in[9];
  const float* w_hh1 = (const float*)d_in[10];
  const float* b_ih1 = (const float*)d_in[11];
  const float* b_hh1 = (const float*)d_in[12];
  const float* post_w = (const float*)d_in[13];
  const float* post_b = (const float*)d_in[14];
  float* out = (float*)d_out;
  char* ws = (char*)d_ws;

  u16*   WcP   = (u16*)(ws + 0);        // 65536 B
  u16*   WhhP0 = (u16*)(ws + 65536);    // 131072 B
  u16*   WihP1 = (u16*)(ws + 196608);   // 131072 B
  u16*   WhhP1 = (u16*)(ws + 327680);   // 131072 B
  float* bias0 = (float*)(ws + 458752); // 2048 B
  float* bias1 = (float*)(ws + 460800); // 2048 B
  u16*   xb    = (u16*)(ws + 462848);   // 33554432 B  (x_in as bf16)
  u16*   y0    = (u16*)(ws + 34017280); // 67108864 B

  conv_x_kernel<<<dim3(16384), dim3(256), 0, stream>>>(x_in, xb);
  prep_kernel<<<dim3(256), dim3(256), 0, stream>>>(
      pre_w, pre_b, w_ih0, w_hh0, b_ih0, b_hh0, w_ih1, w_hh1, b_ih1, b_hh1,
      WcP, WhhP0, WihP1, WhhP1, bias0, bias1);
  lstm_scan<2, true, false><<<dim3(64), dim3(1024), 0, stream>>>(
      xb, WcP, WhhP0, bias0, h0, c0, y0, out, post_w, post_b);
  lstm_scan<4, false, true><<<dim3(64), dim3(1024), 0, stream>>>(
      y0, WihP1, WhhP1, bias1, h0, c0, y0, out, post_w, post_b);
}

// Round 6
// 1462.254 us; speedup vs baseline: 1.1427x; 1.1427x over previous
//
#include <hip/hip_runtime.h>

typedef unsigned short u16;
typedef unsigned int   u32;
typedef short  bf16x8 __attribute__((ext_vector_type(8)));
typedef float  f32x4  __attribute__((ext_vector_type(4)));

#define T_SEQ 256
#define BATCH 1024
#define HID   128

__device__ __forceinline__ u16 f2bf(float f) {
  u32 x = __builtin_bit_cast(u32, f);
  x = x + 0x7fffu + ((x >> 16) & 1u);   // round-to-nearest-even
  return (u16)(x >> 16);
}
__device__ __forceinline__ float sigm(float x) {
  return 1.0f / (1.0f + __expf(-x));
}
__device__ __forceinline__ float tanh_f(float x) {
  return 2.0f / (1.0f + __expf(-2.0f * x)) - 1.0f;
}

// ---------------------------------------------------------------------------
// Convert x_in fp32 -> bf16 (4/thread) + zero the 64 producer->consumer flags.
// ---------------------------------------------------------------------------
__global__ void conv_x_kernel(const float* __restrict__ x_in, u16* __restrict__ xb,
                              u32* __restrict__ flags) {
  if (blockIdx.x == 0 && threadIdx.x < 64) flags[threadIdx.x] = 0;
  int i = (blockIdx.x * blockDim.x + threadIdx.x) * 4;
  float4 v = *(const float4*)(x_in + i);
  u32 lo = (u32)f2bf(v.x) | ((u32)f2bf(v.y) << 16);
  u32 hi = (u32)f2bf(v.z) | ((u32)f2bf(v.w) << 16);
  *(u32*)(xb + i) = lo;
  *(u32*)(xb + i + 2) = hi;
}

// ---------------------------------------------------------------------------
// Prep (PERMUTED gate layout — compute-validated in R2/R3/R4 equivalence).
// Wave n owns h-cols [n*8,n*8+8): tile0 = i|f halves, tile1 = g|o halves.
//   col=lane&15, quad=lane>>4, gate t = tile*2+(col>>3), j=col&7
//   orig row r = t*128 + n*8 + j ; k = kk*32 + quad*8 + e
// WcP = w_ih0 @ pre_w (K=64, KK=2); bias0 = w_ih0@pre_b + b_ih0 + b_hh0.
// ---------------------------------------------------------------------------
__global__ void prep_kernel(const float* __restrict__ pre_w, const float* __restrict__ pre_b,
                            const float* __restrict__ w_ih0, const float* __restrict__ w_hh0,
                            const float* __restrict__ b_ih0, const float* __restrict__ b_hh0,
                            const float* __restrict__ w_ih1, const float* __restrict__ w_hh1,
                            const float* __restrict__ b_ih1, const float* __restrict__ b_hh1,
                            u16* __restrict__ WcP, u16* __restrict__ WhhP0,
                            u16* __restrict__ WihP1, u16* __restrict__ WhhP1,
                            float* __restrict__ bias0, float* __restrict__ bias1) {
  const int TOT = 230400;
  for (int idx = blockIdx.x * blockDim.x + threadIdx.x; idx < TOT;
       idx += gridDim.x * blockDim.x) {
    if (idx < 32768) {                       // WcP (KK=2)
      int e = idx & 7, lane = (idx >> 3) & 63, kk = (idx >> 9) & 1,
          tile = (idx >> 10) & 1, n = idx >> 11;
      int col = lane & 15, quad = lane >> 4;
      int r = (tile * 2 + (col >> 3)) * 128 + n * 8 + (col & 7);
      int k = kk * 32 + quad * 8 + e;
      float s = 0.f;
      for (int h = 0; h < 128; ++h)
        s += w_ih0[r * 128 + h] * pre_w[h * 64 + k];
      WcP[idx] = f2bf(s);
    } else if (idx < 33280) {                // bias0 permuted (fp32)
      int p = idx - 32768;
      int col = p & 15, tile = (p >> 4) & 1, n = p >> 5;
      int r = (tile * 2 + (col >> 3)) * 128 + n * 8 + (col & 7);
      float s = b_ih0[r] + b_hh0[r];
      for (int h = 0; h < 128; ++h)
        s += w_ih0[r * 128 + h] * pre_b[h];
      bias0[p] = s;
    } else if (idx < 229888) {               // 3 permuted bf16 copies (KK=4)
      int q = idx - 33280;
      int mat = q / 65536; q = q % 65536;
      int e = q & 7, lane = (q >> 3) & 63, kk = (q >> 9) & 3,
          tile = (q >> 11) & 1, n = q >> 12;
      int col = lane & 15, quad = lane >> 4;
      int r = (tile * 2 + (col >> 3)) * 128 + n * 8 + (col & 7);
      int k = kk * 32 + quad * 8 + e;
      const float* src = mat == 0 ? w_hh0 : (mat == 1 ? w_ih1 : w_hh1);
      u16* dst = mat == 0 ? WhhP0 : (mat == 1 ? WihP1 : WhhP1);
      dst[q] = f2bf(src[r * 128 + k]);
    } else {                                 // bias1 permuted (fp32)
      int p = idx - 229888;
      int col = p & 15, tile = (p >> 4) & 1, n = p >> 5;
      int r = (tile * 2 + (col >> 3)) * 128 + n * 8 + (col & 7);
      bias1[p] = b_ih1[r] + b_hh1[r];
    }
  }
}

// ---------------------------------------------------------------------------
// Fused pipelined 2-layer LSTM. 128 WGs: role = bid>>6 (0=layer0 producer,
// 1=layer1 consumer), blk = bid&63, 16 batch rows each. Single-barrier step
// (validated R2/R3 structure): permuted weights in VGPRs, xor-swizzled bf16
// hbuf double-buffer, shfl_xor(8) gate exchange, fp32 c/h in registers.
// Producer publishes y0[t] + flag (release, one step late so vmcnt drained);
// consumer tid0 spin-acquires flag, then reads y0.
// ---------------------------------------------------------------------------
template <int KKI, bool PROD>
__device__ __forceinline__ void scan_role(
    const u16* __restrict__ xsrc, const u16* __restrict__ WihF,
    const u16* __restrict__ WhhF, const float* __restrict__ biasP,
    const float* __restrict__ h0_in, const float* __restrict__ c0_in,
    u16* __restrict__ y_out, u32* flag, float* __restrict__ dout,
    const float* __restrict__ post_w, const float* __restrict__ post_b,
    int b0, u32 (*hbuf)[1024], float (*h32)[130]) {
  constexpr int KIN = KKI * 32;
  constexpr int LAYER = PROD ? 0 : 1;
  const int tid = threadIdx.x, wave = tid >> 6, lane = tid & 63;
  const int col = lane & 15, quad = lane >> 4;

  bf16x8 wih[2][KKI], whh[2][4];
#pragma unroll
  for (int t2 = 0; t2 < 2; ++t2)
#pragma unroll
    for (int kk = 0; kk < KKI; ++kk)
      wih[t2][kk] = *(const bf16x8*)(WihF + (((wave * 2 + t2) * KKI + kk) * 64 + lane) * 8);
#pragma unroll
  for (int t2 = 0; t2 < 2; ++t2)
#pragma unroll
    for (int kk = 0; kk < 4; ++kk)
      whh[t2][kk] = *(const bf16x8*)(WhhF + (((wave * 2 + t2) * 4 + kk) * 64 + lane) * 8);
  const float bias_t0 = biasP[wave * 32 + col];
  const float bias_t1 = biasP[wave * 32 + 16 + col];

  const int hi = col >> 3;          // lo lanes finish rows 0,1; hi lanes rows 2,3
  const int rbase = hi * 2;
  const int jcol = wave * 8 + (col & 7);

  float cst[2], hf[2];
#pragma unroll
  for (int rr = 0; rr < 2; ++rr) {
    cst[rr] = c0_in[(LAYER * BATCH + b0 + quad * 4 + rbase + rr) * HID + jcol];
    hf[rr]  = h0_in[(LAYER * BATCH + b0 + quad * 4 + rbase + rr) * HID + jcol];
  }

  {  // init hbuf[0] = h0 (swizzled bf16)
    const float* src = h0_in + (LAYER * BATCH + b0 + wave) * HID + lane * 2;
    u32 v = (u32)f2bf(src[0]) | ((u32)f2bf(src[1]) << 16);
    hbuf[0][wave * 64 + (((lane >> 2) ^ wave) << 2) + (lane & 3)] = v;
  }
  __syncthreads();

  const u16* xrow = xsrc + (b0 + col) * KIN;

  for (int t = 0; t < T_SEQ; ++t) {
    const int cb = t & 1, nb = (t + 1) & 1;
    if (!PROD) {
      if (tid == 0) {
        while (__hip_atomic_load(flag, __ATOMIC_ACQUIRE, __HIP_MEMORY_SCOPE_AGENT) <
               (u32)(t + 1))
          __builtin_amdgcn_s_sleep(8);
      }
      __syncthreads();   // orders the acquire/L2-inv before y0 reads
    }
    bf16x8 ax[KKI], ah[4];
#pragma unroll
    for (int kk = 0; kk < KKI; ++kk)
      ax[kk] = *(const bf16x8*)(xrow + kk * 32 + quad * 8);
#pragma unroll
    for (int kk = 0; kk < 4; ++kk)
      ah[kk] = *(const bf16x8*)((const char*)&hbuf[cb][0] + col * 256 +
                                (((kk * 4 + quad) ^ col) << 4));
    f32x4 acc0 = {bias_t0, bias_t0, bias_t0, bias_t0};
    f32x4 acc1 = {bias_t1, bias_t1, bias_t1, bias_t1};
#pragma unroll
    for (int kk = 0; kk < KKI; ++kk) {
      acc0 = __builtin_amdgcn_mfma_f32_16x16x32_bf16(ax[kk], wih[0][kk], acc0, 0, 0, 0);
      acc1 = __builtin_amdgcn_mfma_f32_16x16x32_bf16(ax[kk], wih[1][kk], acc1, 0, 0, 0);
    }
#pragma unroll
    for (int kk = 0; kk < 4; ++kk) {
      acc0 = __builtin_amdgcn_mfma_f32_16x16x32_bf16(ah[kk], whh[0][kk], acc0, 0, 0, 0);
      acc1 = __builtin_amdgcn_mfma_f32_16x16x32_bf16(ah[kk], whh[1][kk], acc1, 0, 0, 0);
    }
    // validated exchange: lo lanes finish rows {0,1}, hi lanes {2,3}
#pragma unroll
    for (int rr = 0; rr < 2; ++rr) {
      float a_lo0 = acc0[rr], a_hi0 = acc0[2 + rr];
      float a_lo1 = acc1[rr], a_hi1 = acc1[2 + rr];
      float send0 = hi ? a_lo0 : a_hi0;
      float send1 = hi ? a_lo1 : a_hi1;
      float recv0 = __shfl_xor(send0, 8, 64);
      float recv1 = __shfl_xor(send1, 8, 64);
      float keep0 = hi ? a_hi0 : a_lo0;
      float keep1 = hi ? a_hi1 : a_lo1;
      float iv = hi ? recv0 : keep0;
      float fv = hi ? keep0 : recv0;
      float gv = hi ? recv1 : keep1;
      float ov = hi ? keep1 : recv1;
      float si = sigm(iv), sf = sigm(fv), tg = tanh_f(gv), so = sigm(ov);
      float cn = sf * cst[rr] + si * tg;
      cst[rr] = cn;
      hf[rr] = so * tanh_f(cn);
      int m = quad * 4 + rbase + rr;
      *(u16*)((char*)&hbuf[nb][0] + m * 256 + ((wave ^ m) << 4) + (col & 7) * 2) =
          f2bf(hf[rr]);
    }
    __syncthreads();
    if (PROD) {
      u32 v = hbuf[nb][wave * 64 + (((lane >> 2) ^ wave) << 2) + (lane & 3)];
      *(u32*)(y_out + (t * BATCH + b0 + wave) * HID + lane * 2) = v;
      // publish one step late: this barrier's vmcnt(0) drained step t-1's y stores
      if (tid == 0 && t > 0) {
        __threadfence();
        __hip_atomic_store(flag, (u32)t, __ATOMIC_RELEASE, __HIP_MEMORY_SCOPE_AGENT);
      }
    }
    xrow += BATCH * KIN;
  }
  if (PROD) {
    __syncthreads();   // drain final y stores
    if (tid == 0) {
      __threadfence();
      __hip_atomic_store(flag, (u32)T_SEQ, __ATOMIC_RELEASE, __HIP_MEMORY_SCOPE_AGENT);
    }
  }

  // ---- finals from fp32 registers ----
#pragma unroll
  for (int rr = 0; rr < 2; ++rr) {
    int m = quad * 4 + rbase + rr;
    dout[BATCH + LAYER * (BATCH * HID) + (b0 + m) * HID + jcol] = hf[rr];
    dout[BATCH + 2 * BATCH * HID + LAYER * (BATCH * HID) + (b0 + m) * HID + jcol] = cst[rr];
  }

  if (!PROD) {  // pred via fp32 LDS stage
#pragma unroll
    for (int rr = 0; rr < 2; ++rr)
      h32[quad * 4 + rbase + rr][jcol] = hf[rr];
    __syncthreads();
    float a0 = fmaxf(h32[wave][2 * lane], 0.f);
    float a1 = fmaxf(h32[wave][2 * lane + 1], 0.f);
    float p = a0 * post_w[2 * lane] + a1 * post_w[2 * lane + 1];
#pragma unroll
    for (int off = 32; off > 0; off >>= 1) p += __shfl_down(p, off, 64);
    if (lane == 0) dout[b0 + wave] = p + post_b[0];
  }
}

__global__ __launch_bounds__(1024) void lstm_fused(
    const u16* __restrict__ xb,
    const u16* __restrict__ WcP, const u16* __restrict__ WhhP0,
    const float* __restrict__ bias0,
    const u16* __restrict__ WihP1, const u16* __restrict__ WhhP1,
    const float* __restrict__ bias1,
    const float* __restrict__ h0_in, const float* __restrict__ c0_in,
    u16* __restrict__ y0, u32* __restrict__ flags, float* __restrict__ dout,
    const float* __restrict__ post_w, const float* __restrict__ post_b) {
  __shared__ __align__(16) u32 hbuf[2][1024];
  __shared__ float h32[16][130];
  const int role = blockIdx.x >> 6;      // pairs (L0 b, L1 b) land on same XCD (64%8==0)
  const int blk = blockIdx.x & 63;
  const int b0 = blk * 16;
  if (role == 0)
    scan_role<2, true>(xb, WcP, WhhP0, bias0, h0_in, c0_in, y0, &flags[blk], dout,
                       post_w, post_b, b0, hbuf, h32);
  else
    scan_role<4, false>(y0, WihP1, WhhP1, bias1, h0_in, c0_in, y0, &flags[blk], dout,
                        post_w, post_b, b0, hbuf, h32);
}

extern "C" void kernel_launch(void* const* d_in, const int* in_sizes, int n_in,
                              void* d_out, int out_size, void* d_ws, size_t ws_size,
                              hipStream_t stream) {
  const float* x_in  = (const float*)d_in[0];
  const float* h0    = (const float*)d_in[1];
  const float* c0    = (const float*)d_in[2];
  const float* pre_w = (const float*)d_in[3];
  const float* pre_b = (const float*)d_in[4];
  const float* w_ih0 = (const float*)d_in[5];
  const float* w_hh0 = (const float*)d_in[6];
  const float* b_ih0 = (const float*)d_in[7];
  const float* b_hh0 = (const float*)d_in[8];
  const float* w_ih1 = (const float*)d_in[9];
  const float* w_hh1 = (const float*)d_in[10];
  const float* b_ih1 = (const float*)d_in[11];
  const float* b_hh1 = (const float*)d_in[12];
  const float* post_w = (const float*)d_in[13];
  const float* post_b = (const float*)d_in[14];
  float* out = (float*)d_out;
  char* ws = (char*)d_ws;

  u16*   WcP   = (u16*)(ws + 0);        // 65536 B
  u16*   WhhP0 = (u16*)(ws + 65536);    // 131072 B
  u16*   WihP1 = (u16*)(ws + 196608);   // 131072 B
  u16*   WhhP1 = (u16*)(ws + 327680);   // 131072 B
  float* bias0 = (float*)(ws + 458752); // 2048 B
  float* bias1 = (float*)(ws + 460800); // 2048 B
  u32*   flags = (u32*)(ws + 462848);   // 256 B
  u16*   xb    = (u16*)(ws + 463104);   // 33554432 B
  u16*   y0    = (u16*)(ws + 34017536); // 67108864 B

  conv_x_kernel<<<dim3(16384), dim3(256), 0, stream>>>(x_in, xb, flags);
  prep_kernel<<<dim3(256), dim3(256), 0, stream>>>(
      pre_w, pre_b, w_ih0, w_hh0, b_ih0, b_hh0, w_ih1, w_hh1, b_ih1, b_hh1,
      WcP, WhhP0, WihP1, WhhP1, bias0, bias1);
  lstm_fused<<<dim3(128), dim3(1024), 0, stream>>>(
      xb, WcP, WhhP0, bias0, WihP1, WhhP1, bias1, h0, c0, y0, flags, out,
      post_w, post_b);
}

// Round 7
// 912.840 us; speedup vs baseline: 1.8304x; 1.6019x over previous
//
#include <hip/hip_runtime.h>

typedef unsigned short u16;
typedef unsigned int   u32;
typedef short  bf16x8 __attribute__((ext_vector_type(8)));
typedef float  f32x4  __attribute__((ext_vector_type(4)));

#define T_SEQ 256
#define BATCH 1024
#define HID   128

__device__ __forceinline__ u16 f2bf(float f) {
  u32 x = __builtin_bit_cast(u32, f);
  x = x + 0x7fffu + ((x >> 16) & 1u);   // round-to-nearest-even
  return (u16)(x >> 16);
}
__device__ __forceinline__ float sigm(float x) {
  return __builtin_amdgcn_rcpf(1.0f + __expf(-x));
}
__device__ __forceinline__ float tanh_f(float x) {
  return 2.0f * __builtin_amdgcn_rcpf(1.0f + __expf(-2.0f * x)) - 1.0f;
}

// ---------------------------------------------------------------------------
// Convert x_in fp32 -> bf16 (4/thread) + zero the 64 producer->consumer flags.
// ---------------------------------------------------------------------------
__global__ void conv_x_kernel(const float* __restrict__ x_in, u16* __restrict__ xb,
                              u32* __restrict__ flags) {
  if (blockIdx.x == 0 && threadIdx.x < 64) flags[threadIdx.x] = 0;
  int i = (blockIdx.x * blockDim.x + threadIdx.x) * 4;
  float4 v = *(const float4*)(x_in + i);
  u32 lo = (u32)f2bf(v.x) | ((u32)f2bf(v.y) << 16);
  u32 hi = (u32)f2bf(v.z) | ((u32)f2bf(v.w) << 16);
  *(u32*)(xb + i) = lo;
  *(u32*)(xb + i + 2) = hi;
}

// ---------------------------------------------------------------------------
// Prep (PERMUTED gate layout — compute-validated R2-R4).
// Wave n owns h-cols [n*8,n*8+8): tile0 = i|f halves, tile1 = g|o halves.
//   col=lane&15, quad=lane>>4, gate t = tile*2+(col>>3), j=col&7
//   orig row r = t*128 + n*8 + j ; k = kk*32 + quad*8 + e
// WcP = w_ih0 @ pre_w (K=64, KK=2); bias0 = w_ih0@pre_b + b_ih0 + b_hh0.
// ---------------------------------------------------------------------------
__global__ void prep_kernel(const float* __restrict__ pre_w, const float* __restrict__ pre_b,
                            const float* __restrict__ w_ih0, const float* __restrict__ w_hh0,
                            const float* __restrict__ b_ih0, const float* __restrict__ b_hh0,
                            const float* __restrict__ w_ih1, const float* __restrict__ w_hh1,
                            const float* __restrict__ b_ih1, const float* __restrict__ b_hh1,
                            u16* __restrict__ WcP, u16* __restrict__ WhhP0,
                            u16* __restrict__ WihP1, u16* __restrict__ WhhP1,
                            float* __restrict__ bias0, float* __restrict__ bias1) {
  const int TOT = 230400;
  for (int idx = blockIdx.x * blockDim.x + threadIdx.x; idx < TOT;
       idx += gridDim.x * blockDim.x) {
    if (idx < 32768) {                       // WcP (KK=2)
      int e = idx & 7, lane = (idx >> 3) & 63, kk = (idx >> 9) & 1,
          tile = (idx >> 10) & 1, n = idx >> 11;
      int col = lane & 15, quad = lane >> 4;
      int r = (tile * 2 + (col >> 3)) * 128 + n * 8 + (col & 7);
      int k = kk * 32 + quad * 8 + e;
      float s = 0.f;
      for (int h = 0; h < 128; ++h)
        s += w_ih0[r * 128 + h] * pre_w[h * 64 + k];
      WcP[idx] = f2bf(s);
    } else if (idx < 33280) {                // bias0 permuted (fp32)
      int p = idx - 32768;
      int col = p & 15, tile = (p >> 4) & 1, n = p >> 5;
      int r = (tile * 2 + (col >> 3)) * 128 + n * 8 + (col & 7);
      float s = b_ih0[r] + b_hh0[r];
      for (int h = 0; h < 128; ++h)
        s += w_ih0[r * 128 + h] * pre_b[h];
      bias0[p] = s;
    } else if (idx < 229888) {               // 3 permuted bf16 copies (KK=4)
      int q = idx - 33280;
      int mat = q / 65536; q = q % 65536;
      int e = q & 7, lane = (q >> 3) & 63, kk = (q >> 9) & 3,
          tile = (q >> 11) & 1, n = q >> 12;
      int col = lane & 15, quad = lane >> 4;
      int r = (tile * 2 + (col >> 3)) * 128 + n * 8 + (col & 7);
      int k = kk * 32 + quad * 8 + e;
      const float* src = mat == 0 ? w_hh0 : (mat == 1 ? w_ih1 : w_hh1);
      u16* dst = mat == 0 ? WhhP0 : (mat == 1 ? WihP1 : WhhP1);
      dst[q] = f2bf(src[r * 128 + k]);
    } else {                                 // bias1 permuted (fp32)
      int p = idx - 229888;
      int col = p & 15, tile = (p >> 4) & 1, n = p >> 5;
      int r = (tile * 2 + (col >> 3)) * 128 + n * 8 + (col & 7);
      bias1[p] = b_ih1[r] + b_hh1[r];
    }
  }
}

// ---------------------------------------------------------------------------
// Fused pipelined 2-layer LSTM. 128 WGs: role = bid>>6 (0=L0 producer,
// 1=L1 consumer), blk = bid&63, 16 batch rows each. Weight-stationary in
// VGPRs (launch_bounds(1024,4) -> 128-VGPR budget; producer ~106, consumer
// ~124). Flag published every 4 steps (release/acquire, agent scope) to
// amortize L2 wb/inv; consumer lags 4-7 steps.
// ---------------------------------------------------------------------------
template <int KKI, bool PROD>
__device__ __forceinline__ void scan_role(
    const u16* __restrict__ xsrc, const u16* __restrict__ WihF,
    const u16* __restrict__ WhhF, const float* __restrict__ biasP,
    const float* __restrict__ h0_in, const float* __restrict__ c0_in,
    u16* __restrict__ y_out, u32* flag, float* __restrict__ dout,
    const float* __restrict__ post_w, const float* __restrict__ post_b,
    int b0, u32 (*hbuf)[1024], float (*h32)[130]) {
  constexpr int KIN = KKI * 32;
  constexpr int LAYER = PROD ? 0 : 1;
  const int tid = threadIdx.x, wave = tid >> 6, lane = tid & 63;
  const int col = lane & 15, quad = lane >> 4;

  bf16x8 wih[2][KKI], whh[2][4];
#pragma unroll
  for (int t2 = 0; t2 < 2; ++t2)
#pragma unroll
    for (int kk = 0; kk < KKI; ++kk)
      wih[t2][kk] = *(const bf16x8*)(WihF + (((wave * 2 + t2) * KKI + kk) * 64 + lane) * 8);
#pragma unroll
  for (int t2 = 0; t2 < 2; ++t2)
#pragma unroll
    for (int kk = 0; kk < 4; ++kk)
      whh[t2][kk] = *(const bf16x8*)(WhhF + (((wave * 2 + t2) * 4 + kk) * 64 + lane) * 8);
  const float bias_t0 = biasP[wave * 32 + col];
  const float bias_t1 = biasP[wave * 32 + 16 + col];

  const int hi = col >> 3;          // lo lanes finish rows 0,1; hi lanes rows 2,3
  const int rbase = hi * 2;
  const int jcol = wave * 8 + (col & 7);

  float cst[2], hf[2];
#pragma unroll
  for (int rr = 0; rr < 2; ++rr) {
    cst[rr] = c0_in[(LAYER * BATCH + b0 + quad * 4 + rbase + rr) * HID + jcol];
    hf[rr]  = h0_in[(LAYER * BATCH + b0 + quad * 4 + rbase + rr) * HID + jcol];
  }

  {  // init hbuf[0] = h0 (swizzled bf16)
    const float* src = h0_in + (LAYER * BATCH + b0 + wave) * HID + lane * 2;
    u32 v = (u32)f2bf(src[0]) | ((u32)f2bf(src[1]) << 16);
    hbuf[0][wave * 64 + (((lane >> 2) ^ wave) << 2) + (lane & 3)] = v;
  }
  __syncthreads();

  const u16* xrow = xsrc + (b0 + col) * KIN;

  for (int t = 0; t < T_SEQ; ++t) {
    const int cb = t & 1, nb = (t + 1) & 1;
    if (!PROD) {
      if (tid == 0) {
        while (__hip_atomic_load(flag, __ATOMIC_ACQUIRE, __HIP_MEMORY_SCOPE_AGENT) <
               (u32)(t + 1))
          __builtin_amdgcn_s_sleep(8);
      }
      __syncthreads();   // orders the acquire/inv before y0 reads
    }
    bf16x8 ax[KKI], ah[4];
#pragma unroll
    for (int kk = 0; kk < KKI; ++kk)
      ax[kk] = *(const bf16x8*)(xrow + kk * 32 + quad * 8);
#pragma unroll
    for (int kk = 0; kk < 4; ++kk)
      ah[kk] = *(const bf16x8*)((const char*)&hbuf[cb][0] + col * 256 +
                                (((kk * 4 + quad) ^ col) << 4));
    f32x4 acc0 = {bias_t0, bias_t0, bias_t0, bias_t0};
    f32x4 acc1 = {bias_t1, bias_t1, bias_t1, bias_t1};
#pragma unroll
    for (int kk = 0; kk < KKI; ++kk) {
      acc0 = __builtin_amdgcn_mfma_f32_16x16x32_bf16(ax[kk], wih[0][kk], acc0, 0, 0, 0);
      acc1 = __builtin_amdgcn_mfma_f32_16x16x32_bf16(ax[kk], wih[1][kk], acc1, 0, 0, 0);
    }
#pragma unroll
    for (int kk = 0; kk < 4; ++kk) {
      acc0 = __builtin_amdgcn_mfma_f32_16x16x32_bf16(ah[kk], whh[0][kk], acc0, 0, 0, 0);
      acc1 = __builtin_amdgcn_mfma_f32_16x16x32_bf16(ah[kk], whh[1][kk], acc1, 0, 0, 0);
    }
    // validated exchange: lo lanes finish rows {0,1}, hi lanes {2,3}
#pragma unroll
    for (int rr = 0; rr < 2; ++rr) {
      float a_lo0 = acc0[rr], a_hi0 = acc0[2 + rr];
      float a_lo1 = acc1[rr], a_hi1 = acc1[2 + rr];
      float send0 = hi ? a_lo0 : a_hi0;
      float send1 = hi ? a_lo1 : a_hi1;
      float recv0 = __shfl_xor(send0, 8, 64);
      float recv1 = __shfl_xor(send1, 8, 64);
      float keep0 = hi ? a_hi0 : a_lo0;
      float keep1 = hi ? a_hi1 : a_lo1;
      float iv = hi ? recv0 : keep0;
      float fv = hi ? keep0 : recv0;
      float gv = hi ? recv1 : keep1;
      float ov = hi ? keep1 : recv1;
      float si = sigm(iv), sf = sigm(fv), tg = tanh_f(gv), so = sigm(ov);
      float cn = sf * cst[rr] + si * tg;
      cst[rr] = cn;
      hf[rr] = so * tanh_f(cn);
      int m = quad * 4 + rbase + rr;
      *(u16*)((char*)&hbuf[nb][0] + m * 256 + ((wave ^ m) << 4) + (col & 7) * 2) =
          f2bf(hf[rr]);
    }
    __syncthreads();
    if (PROD) {
      u32 v = hbuf[nb][wave * 64 + (((lane >> 2) ^ wave) << 2) + (lane & 3)];
      *(u32*)(y_out + (t * BATCH + b0 + wave) * HID + lane * 2) = v;
      // publish every 4 steps; safe same-step: compiler drains vmcnt(0)
      // before s_barrier, so all waves' y0 stores are in L2; the release
      // store performs the agent-scope writeback.
      if (tid == 0 && (t & 3) == 3)
        __hip_atomic_store(flag, (u32)(t + 1), __ATOMIC_RELEASE, __HIP_MEMORY_SCOPE_AGENT);
    }
    xrow += BATCH * KIN;
  }

  // ---- finals from fp32 registers ----
#pragma unroll
  for (int rr = 0; rr < 2; ++rr) {
    int m = quad * 4 + rbase + rr;
    dout[BATCH + LAYER * (BATCH * HID) + (b0 + m) * HID + jcol] = hf[rr];
    dout[BATCH + 2 * BATCH * HID + LAYER * (BATCH * HID) + (b0 + m) * HID + jcol] = cst[rr];
  }

  if (!PROD) {  // pred via fp32 LDS stage
#pragma unroll
    for (int rr = 0; rr < 2; ++rr)
      h32[quad * 4 + rbase + rr][jcol] = hf[rr];
    __syncthreads();
    float a0 = fmaxf(h32[wave][2 * lane], 0.f);
    float a1 = fmaxf(h32[wave][2 * lane + 1], 0.f);
    float p = a0 * post_w[2 * lane] + a1 * post_w[2 * lane + 1];
#pragma unroll
    for (int off = 32; off > 0; off >>= 1) p += __shfl_down(p, off, 64);
    if (lane == 0) dout[b0 + wave] = p + post_b[0];
  }
}

__global__ __launch_bounds__(1024, 4) void lstm_fused(
    const u16* __restrict__ xb,
    const u16* __restrict__ WcP, const u16* __restrict__ WhhP0,
    const float* __restrict__ bias0,
    const u16* __restrict__ WihP1, const u16* __restrict__ WhhP1,
    const float* __restrict__ bias1,
    const float* __restrict__ h0_in, const float* __restrict__ c0_in,
    u16* __restrict__ y0, u32* __restrict__ flags, float* __restrict__ dout,
    const float* __restrict__ post_w, const float* __restrict__ post_b) {
  __shared__ __align__(16) u32 hbuf[2][1024];
  __shared__ float h32[16][130];
  const int role = blockIdx.x >> 6;      // pairs (L0 b, L1 b) land on same XCD (64%8==0)
  const int blk = blockIdx.x & 63;
  const int b0 = blk * 16;
  if (role == 0)
    scan_role<2, true>(xb, WcP, WhhP0, bias0, h0_in, c0_in, y0, &flags[blk], dout,
                       post_w, post_b, b0, hbuf, h32);
  else
    scan_role<4, false>(y0, WihP1, WhhP1, bias1, h0_in, c0_in, y0, &flags[blk], dout,
                        post_w, post_b, b0, hbuf, h32);
}

extern "C" void kernel_launch(void* const* d_in, const int* in_sizes, int n_in,
                              void* d_out, int out_size, void* d_ws, size_t ws_size,
                              hipStream_t stream) {
  const float* x_in  = (const float*)d_in[0];
  const float* h0    = (const float*)d_in[1];
  const float* c0    = (const float*)d_in[2];
  const float* pre_w = (const float*)d_in[3];
  const float* pre_b = (const float*)d_in[4];
  const float* w_ih0 = (const float*)d_in[5];
  const float* w_hh0 = (const float*)d_in[6];
  const float* b_ih0 = (const float*)d_in[7];
  const float* b_hh0 = (const float*)d_in[8];
  const float* w_ih1 = (const float*)d_in[9];
  const float* w_hh1 = (const float*)d_in[10];
  const float* b_ih1 = (const float*)d_in[11];
  const float* b_hh1 = (const float*)d_in[12];
  const float* post_w = (const float*)d_in[13];
  const float* post_b = (const float*)d_in[14];
  float* out = (float*)d_out;
  char* ws = (char*)d_ws;

  u16*   WcP   = (u16*)(ws + 0);        // 65536 B
  u16*   WhhP0 = (u16*)(ws + 65536);    // 131072 B
  u16*   WihP1 = (u16*)(ws + 196608);   // 131072 B
  u16*   WhhP1 = (u16*)(ws + 327680);   // 131072 B
  float* bias0 = (float*)(ws + 458752); // 2048 B
  float* bias1 = (float*)(ws + 460800); // 2048 B
  u32*   flags = (u32*)(ws + 462848);   // 256 B
  u16*   xb    = (u16*)(ws + 463104);   // 33554432 B
  u16*   y0    = (u16*)(ws + 34017536); // 67108864 B

  conv_x_kernel<<<dim3(16384), dim3(256), 0, stream>>>(x_in, xb, flags);
  prep_kernel<<<dim3(256), dim3(256), 0, stream>>>(
      pre_w, pre_b, w_ih0, w_hh0, b_ih0, b_hh0, w_ih1, w_hh1, b_ih1, b_hh1,
      WcP, WhhP0, WihP1, WhhP1, bias0, bias1);
  lstm_fused<<<dim3(128), dim3(1024), 0, stream>>>(
      xb, WcP, WhhP0, bias0, WihP1, WhhP1, bias1, h0, c0, y0, flags, out,
      post_w, post_b);
}